// Round 2
// baseline (341.080 us; speedup 1.0000x reference)
//
#include <hip/hip_runtime.h>
#include <hip/hip_bf16.h>

#define EPS 1e-8f

__device__ __forceinline__ float dot16(const float* __restrict__ a,
                                       const float* __restrict__ b) {
    const float4* a4 = (const float4*)a;
    const float4* b4 = (const float4*)b;
    float4 a0 = a4[0], a1 = a4[1], a2 = a4[2], a3 = a4[3];
    float4 b0 = b4[0], b1 = b4[1], b2 = b4[2], b3 = b4[3];
    return a0.x * b0.x + a0.y * b0.y + a0.z * b0.z + a0.w * b0.w
         + a1.x * b1.x + a1.y * b1.y + a1.z * b1.z + a1.w * b1.w
         + a2.x * b2.x + a2.y * b2.y + a2.z * b2.z + a2.w * b2.w
         + a3.x * b3.x + a3.y * b3.y + a3.z * b3.z + a3.w * b3.w;
}

__device__ __forceinline__ float sigmoidf_(float x) {
    return 1.0f / (1.0f + __expf(-x));
}

// Pass 1: 4 edges/thread. score -> sigmoid -> w, HW-atomic row_sum[src] += w
__global__ __launch_bounds__(256) void edge_w_kernel(
    const int* __restrict__ src, const int* __restrict__ dst,
    const float* __restrict__ emb1, const float* __restrict__ emb2,
    float* __restrict__ w, float* __restrict__ row_sum, int n_edges)
{
    int t = blockIdx.x * blockDim.x + threadIdx.x;
    int e0 = t * 4;
    if (e0 + 3 < n_edges) {
        int4 s = ((const int4*)src)[t];
        int4 d = ((const int4*)dst)[t];
        float sc0 = dot16(emb1 + (size_t)s.x * 16, emb2 + (size_t)d.x * 16);
        float sc1 = dot16(emb1 + (size_t)s.y * 16, emb2 + (size_t)d.y * 16);
        float sc2 = dot16(emb1 + (size_t)s.z * 16, emb2 + (size_t)d.z * 16);
        float sc3 = dot16(emb1 + (size_t)s.w * 16, emb2 + (size_t)d.w * 16);
        float4 wv;
        wv.x = sigmoidf_(sc0);
        wv.y = sigmoidf_(sc1);
        wv.z = sigmoidf_(sc2);
        wv.w = sigmoidf_(sc3);
        ((float4*)w)[t] = wv;
        unsafeAtomicAdd(&row_sum[s.x], wv.x);
        unsafeAtomicAdd(&row_sum[s.y], wv.y);
        unsafeAtomicAdd(&row_sum[s.z], wv.z);
        unsafeAtomicAdd(&row_sum[s.w], wv.w);
    } else if (e0 < n_edges) {
        for (int e = e0; e < n_edges; ++e) {
            int s = src[e], d = dst[e];
            float wv = sigmoidf_(dot16(emb1 + (size_t)s * 16, emb2 + (size_t)d * 16));
            w[e] = wv;
            unsafeAtomicAdd(&row_sum[s], wv);
        }
    }
}

// Pass 2: 4 edges/thread normalize
__global__ __launch_bounds__(256) void edge_norm_kernel(
    const int* __restrict__ src, const float* __restrict__ w,
    const float* __restrict__ row_sum, float* __restrict__ out, int n_edges)
{
    int t = blockIdx.x * blockDim.x + threadIdx.x;
    int e0 = t * 4;
    if (e0 + 3 < n_edges) {
        int4 s = ((const int4*)src)[t];
        float4 wv = ((const float4*)w)[t];
        float r0 = row_sum[s.x];
        float r1 = row_sum[s.y];
        float r2 = row_sum[s.z];
        float r3 = row_sum[s.w];
        float4 o;
        o.x = wv.x / (r0 + EPS);
        o.y = wv.y / (r1 + EPS);
        o.z = wv.z / (r2 + EPS);
        o.w = wv.w / (r3 + EPS);
        ((float4*)out)[t] = o;
    } else if (e0 < n_edges) {
        for (int e = e0; e < n_edges; ++e) {
            out[e] = w[e] / (row_sum[src[e]] + EPS);
        }
    }
}

extern "C" void kernel_launch(void* const* d_in, const int* in_sizes, int n_in,
                              void* d_out, int out_size, void* d_ws, size_t ws_size,
                              hipStream_t stream) {
    const int*   src  = (const int*)d_in[0];
    const int*   dst  = (const int*)d_in[1];
    const float* emb1 = (const float*)d_in[2];
    const float* emb2 = (const float*)d_in[3];
    float* out = (float*)d_out;

    int n_edges = in_sizes[0];
    int n_nodes = in_sizes[2] / 16;

    // workspace layout: [row_sum: n_nodes floats][w: n_edges floats]
    float* row_sum = (float*)d_ws;
    float* w       = row_sum + n_nodes;

    hipMemsetAsync(row_sum, 0, (size_t)n_nodes * sizeof(float), stream);

    int n4 = (n_edges + 3) / 4;
    int block = 256;
    int grid = (n4 + block - 1) / block;
    edge_w_kernel<<<grid, block, 0, stream>>>(src, dst, emb1, emb2, w, row_sum, n_edges);
    edge_norm_kernel<<<grid, block, 0, stream>>>(src, w, row_sum, out, n_edges);
}

// Round 3
// 268.935 us; speedup vs baseline: 1.2683x; 1.2683x over previous
//
#include <hip/hip_runtime.h>
#include <hip/hip_bf16.h>
#include <hip/hip_fp16.h>

#define EPS 1e-8f

// Kernel 0: convert both f32 emb tables to f16 in workspace.
// n2 = number of float2 elements per table (N_NODES*16/2).
__global__ __launch_bounds__(256) void convert_f16_kernel(
    const float2* __restrict__ emb1, const float2* __restrict__ emb2,
    __half2* __restrict__ h1, __half2* __restrict__ h2, int n2)
{
    int i = blockIdx.x * blockDim.x + threadIdx.x;
    if (i < n2) {
        float2 a = emb1[i];
        float2 b = emb2[i];
        h1[i] = __floats2half2_rn(a.x, a.y);
        h2[i] = __floats2half2_rn(b.x, b.y);
    }
}

__device__ __forceinline__ float dot16_h(const uint4* __restrict__ a,
                                         const uint4* __restrict__ b) {
    uint4 A0 = a[0], A1 = a[1];
    uint4 B0 = b[0], B1 = b[1];
    const __half2* pa = (const __half2*)&A0;
    const __half2* pb = (const __half2*)&B0;
    const __half2* qa = (const __half2*)&A1;
    const __half2* qb = (const __half2*)&B1;
    float acc = 0.0f;
#pragma unroll
    for (int i = 0; i < 4; ++i) {
        float2 fa = __half22float2(pa[i]);
        float2 fb = __half22float2(pb[i]);
        acc += fa.x * fb.x + fa.y * fb.y;
        float2 ga = __half22float2(qa[i]);
        float2 gb = __half22float2(qb[i]);
        acc += ga.x * gb.x + ga.y * gb.y;
    }
    return acc;
}

// Pass 1: 1 edge/thread (4-edge/thread regressed L2 locality in R2).
__global__ __launch_bounds__(256) void edge_w_kernel(
    const int* __restrict__ src, const int* __restrict__ dst,
    const __half2* __restrict__ h1, const __half2* __restrict__ h2,
    __half* __restrict__ w, float* __restrict__ row_sum, int n_edges)
{
    int e = blockIdx.x * blockDim.x + threadIdx.x;
    if (e >= n_edges) return;

    int s = src[e];
    int d = dst[e];

    const uint4* a = (const uint4*)(h1 + (size_t)s * 8);  // 32B row
    const uint4* b = (const uint4*)(h2 + (size_t)d * 8);

    float score = dot16_h(a, b);
    float wv = 1.0f / (1.0f + __expf(-score));

    w[e] = __float2half(wv);
    atomicAdd(&row_sum[s], wv);
}

// Pass 2: normalize
__global__ __launch_bounds__(256) void edge_norm_kernel(
    const int* __restrict__ src, const __half* __restrict__ w,
    const float* __restrict__ row_sum, float* __restrict__ out, int n_edges)
{
    int e = blockIdx.x * blockDim.x + threadIdx.x;
    if (e >= n_edges) return;
    int s = src[e];
    out[e] = __half2float(w[e]) / (row_sum[s] + EPS);
}

extern "C" void kernel_launch(void* const* d_in, const int* in_sizes, int n_in,
                              void* d_out, int out_size, void* d_ws, size_t ws_size,
                              hipStream_t stream) {
    const int*   src  = (const int*)d_in[0];
    const int*   dst  = (const int*)d_in[1];
    const float* emb1 = (const float*)d_in[2];
    const float* emb2 = (const float*)d_in[3];
    float* out = (float*)d_out;

    int n_edges = in_sizes[0];
    int n_emb   = in_sizes[2];          // N_NODES * 16 floats
    int n_nodes = n_emb / 16;

    // ws layout (bytes):
    //   [0)                 row_sum : n_nodes f32            (400 KB)
    //   [rs_end)            w       : n_edges f16            (6.4 MB)
    //   [w_end, 16B-aligned) h1     : n_emb f16              (3.2 MB)
    //   [...]               h2      : n_emb f16              (3.2 MB)
    char* base = (char*)d_ws;
    float*   row_sum = (float*)base;
    size_t off = (size_t)n_nodes * sizeof(float);
    __half*  w = (__half*)(base + off);
    off += (size_t)n_edges * sizeof(__half);
    off = (off + 15) & ~(size_t)15;
    __half2* h1 = (__half2*)(base + off);
    off += (size_t)n_emb * sizeof(__half);
    off = (off + 15) & ~(size_t)15;
    __half2* h2 = (__half2*)(base + off);

    hipMemsetAsync(row_sum, 0, (size_t)n_nodes * sizeof(float), stream);

    int block = 256;
    int n2 = n_emb / 2;
    int grid_c = (n2 + block - 1) / block;
    convert_f16_kernel<<<grid_c, block, 0, stream>>>(
        (const float2*)emb1, (const float2*)emb2, h1, h2, n2);

    int grid = (n_edges + block - 1) / block;
    edge_w_kernel<<<grid, block, 0, stream>>>(src, dst, h1, h2, w, row_sum, n_edges);
    edge_norm_kernel<<<grid, block, 0, stream>>>(src, w, row_sum, out, n_edges);
}